// Round 8
// baseline (224.557 us; speedup 1.0000x reference)
//
#include <hip/hip_runtime.h>
#include <hip/hip_fp16.h>
#include <stdint.h>

#define FP8_MAX_V 448.0f
#define BM 256
#define BN 256
#define BKB 128  // K-bytes per tile step (fp8 => 128 elements); LDS row = 128 B

typedef float floatx4 __attribute__((ext_vector_type(4)));
typedef int intx4 __attribute__((ext_vector_type(4)));
typedef int intx8 __attribute__((ext_vector_type(8)));

// asm wait/barrier with full compiler fencing (rule #18).
#define WAITVM(n)                                              \
  do {                                                         \
    asm volatile("s_waitcnt vmcnt(" #n ")" ::: "memory");      \
    __builtin_amdgcn_sched_barrier(0);                         \
  } while (0)
#define BARRIER()                                              \
  do {                                                         \
    __builtin_amdgcn_sched_barrier(0);                         \
    __builtin_amdgcn_s_barrier();                              \
    __builtin_amdgcn_sched_barrier(0);                         \
  } while (0)

// Deterministic bf16 round-to-nearest-even of an fp32 value, returned widened to fp32.
__device__ __forceinline__ float bf16_rne(float v) {
  uint32_t u = __float_as_uint(v);
  u = (u + 0x7fffu + ((u >> 16) & 1u)) & 0xffff0000u;
  return __uint_as_float(u);
}

// Pack 4 fp32 (already clipped to +-448) into 4 OCP e4m3fn bytes via HW RNE cvt.
__device__ __forceinline__ uint32_t pack4_fp8(float a, float b, float c, float d) {
  int p = 0;
  p = __builtin_amdgcn_cvt_pk_fp8_f32(a, b, p, false);  // bytes 0..1
  p = __builtin_amdgcn_cvt_pk_fp8_f32(c, d, p, true);   // bytes 2..3
  return (uint32_t)p;
}

__device__ __forceinline__ void gload_lds16(const uint8_t* g, uint8_t* l) {
  __builtin_amdgcn_global_load_lds(
      (const __attribute__((address_space(1))) uint32_t*)g,
      (__attribute__((address_space(3))) uint32_t*)l,
      16, 0, 0);
}

// Per-row quantization: amax over K -> scale -> fp8. FP16RT: fp16 round-trip the
// scale (weight path, matches reference's scale.astype(fp16).astype(fp32)).
template <bool FP16RT>
__global__ __launch_bounds__(256) void quant_rows_kernel(
    const float* __restrict__ in, uint8_t* __restrict__ out8,
    float* __restrict__ scales, int K) {
  const int row = blockIdx.x;
  const int tid = threadIdx.x;
  const float* rp = in + (size_t)row * K;

  // K = 4096: 16 floats/thread as 4x float4, coalesced (stride-256 float4s).
  float4 v[4];
  float amax = 0.f;
#pragma unroll
  for (int i = 0; i < 4; ++i) {
    v[i] = ((const float4*)rp)[i * 256 + tid];
    amax = fmaxf(amax, fmaxf(fmaxf(fabsf(v[i].x), fabsf(v[i].y)),
                             fmaxf(fabsf(v[i].z), fabsf(v[i].w))));
  }
#pragma unroll
  for (int off = 32; off; off >>= 1) amax = fmaxf(amax, __shfl_xor(amax, off));
  __shared__ float red[4];
  if ((tid & 63) == 0) red[tid >> 6] = amax;
  __syncthreads();
  amax = fmaxf(fmaxf(red[0], red[1]), fmaxf(red[2], red[3]));

  float scale = fmaxf(amax / FP8_MAX_V, 1e-6f);
  if (FP16RT) scale = __half2float(__float2half(scale));  // RNE, matches jnp fp16 round-trip
  if (tid == 0) scales[row] = scale;

  uint32_t* op = (uint32_t*)(out8 + (size_t)row * K);
#pragma unroll
  for (int i = 0; i < 4; ++i) {
    // true fp32 division (correctly rounded) to match numpy's x / scale
    float qa = fminf(fmaxf(v[i].x / scale, -FP8_MAX_V), FP8_MAX_V);
    float qb = fminf(fmaxf(v[i].y / scale, -FP8_MAX_V), FP8_MAX_V);
    float qc = fminf(fmaxf(v[i].z / scale, -FP8_MAX_V), FP8_MAX_V);
    float qd = fminf(fmaxf(v[i].w / scale, -FP8_MAX_V), FP8_MAX_V);
    op[i * 256 + tid] = pack4_fp8(qa, qb, qc, qd);
  }
}

// C[t,o] = sum_k A8[t,k]*B8[o,k]  (both K-major), scaled + bias + bf16 round.
// Round-7 pipeline scaled to 256x256: 512 thr = 8 waves (2M x 4N), per-wave
// 128x64 output = 8x4 frags of MX-scaled mfma_scale_f32_16x16x128_f8f6f4 with
// UNIT scales (e8m0 0x7F = 1.0) -> fp8 e4m3 math at 2x rate, 1 MFMA per
// fragment-pair per 128-K tile. Wave-tile 128x64 cuts LDS bytes/FLOP from
// 1/64 to 1/85: B-frags (4) held across the tile, A-frags streamed in two
// mh-halves -> every fragment ds_read exactly once (24 b128 per wave-tile).
//
// Pipeline (proven r3/r6/r7): 2 LDS buffers (128 KB -> 1 block/CU), 1-tile
// prefetch lead, counted WAITVM(8) at tile head (drains tile t, leaves t+1's
// 8 gloads in flight), 2 barriers/tile, compiler-scheduled inner loop.
// Race-free: slot rewritten only after the barrier ending its reads; slot
// read only after every wave's own WAITVM + barrier.
//
// LDS swizzle (T2, rule #21 both-sides): 16B chunk c16 within each 128B row
// XOR'd with (row&7); linear LDS dest (gload_lds) + pre-swizzled global
// source + swizzled read (fragment = chunks {2*hi, 2*hi+1} ^ (fr&7)).
__global__ __launch_bounds__(512, 2) void gemm_fp8_kernel(
    const uint8_t* __restrict__ A8, const uint8_t* __restrict__ B8,
    const float* __restrict__ asc, const float* __restrict__ wsc,
    const float* __restrict__ bias, float* __restrict__ out,
    int M, int N, int K) {
  __shared__ __align__(16) uint8_t As[2][BM * BKB];  // 2 x 32 KB
  __shared__ __align__(16) uint8_t Bs[2][BN * BKB];  // 2 x 32 KB

  const int tid = threadIdx.x;
  const int lane = tid & 63;
  const int wid = tid >> 6;
  const int wr = wid >> 2;  // 0..1 (M dimension, 128 rows)
  const int wc = wid & 3;   // 0..3 (N dimension, 64 cols)

  const int ntn = N / BN;
  const int bm = blockIdx.x / ntn;
  const int bn = blockIdx.x % ntn;

  floatx4 acc[8][4] = {};

  // Staging: thread tid -> LDS linear offset tid*16 (row=tid>>3, c16_phys=tid&7),
  // global source chunk = c16_phys ^ (row&7). Row stride 64 between the 4 calls
  // preserves (row&7), so one source offset serves all calls.
  const int srow = tid >> 3;                      // 0..63
  const int sc_log = (tid & 7) ^ (srow & 7);      // pre-swizzled source chunk
  const uint8_t* ga0 = A8 + (size_t)(bm * BM + srow) * K + sc_log * 16;
  const uint8_t* gb0 = B8 + (size_t)(bn * BN + srow) * K + sc_log * 16;
  const size_t rstep = (size_t)64 * K;

  const int fr = lane & 15;        // fragment row/col within 16
  const int hi = lane >> 4;        // 0..3: K-block of 32 elems within the 128-tile
  const int fsw = fr & 7;          // read-side swizzle key
  // Lane's 32B fragment = chunks {2*hi, 2*hi+1}, each XOR-swizzled.
  const int cls = ((2 * hi) ^ fsw) * 16;      // low 16B chunk byte offset
  const int chs = ((2 * hi + 1) ^ fsw) * 16;  // high 16B chunk byte offset

  // Stage one K-tile (A: 4 x 16B, B: 4 x 16B per thread) into buffer `buf`.
  auto stage = [&](int buf, int k0) {
    uint8_t* lA = As[buf] + tid * 16;
    uint8_t* lB = Bs[buf] + tid * 16;
#pragma unroll
    for (int i = 0; i < 4; ++i) gload_lds16(ga0 + i * rstep + k0, lA + i * 8192);
#pragma unroll
    for (int i = 0; i < 4; ++i) gload_lds16(gb0 + i * rstep + k0, lB + i * 8192);
  };

  auto compute = [&](int buf) {
    const uint8_t* Ab = As[buf];
    const uint8_t* Bb = Bs[buf];
    intx8 b[4];
#pragma unroll
    for (int n = 0; n < 4; ++n) {
      const uint8_t* p = Bb + (size_t)(wc * 64 + n * 16 + fr) * BKB;
      intx4 lo = *(const intx4*)(p + cls);
      intx4 hh = *(const intx4*)(p + chs);
      b[n] = (intx8){lo.x, lo.y, lo.z, lo.w, hh.x, hh.y, hh.z, hh.w};
    }
#pragma unroll
    for (int mh = 0; mh < 2; ++mh) {
      intx8 a[4];
#pragma unroll
      for (int i = 0; i < 4; ++i) {
        const uint8_t* p = Ab + (size_t)(wr * 128 + (mh * 4 + i) * 16 + fr) * BKB;
        intx4 lo = *(const intx4*)(p + cls);
        intx4 hh = *(const intx4*)(p + chs);
        a[i] = (intx8){lo.x, lo.y, lo.z, lo.w, hh.x, hh.y, hh.z, hh.w};
      }
#pragma unroll
      for (int i = 0; i < 4; ++i)
#pragma unroll
        for (int n = 0; n < 4; ++n)
          // cbsz=0 (A=fp8 e4m3), blgp=0 (B=fp8 e4m3), scales = e8m0 0x7F = 1.0
          acc[mh * 4 + i][n] = __builtin_amdgcn_mfma_scale_f32_16x16x128_f8f6f4(
              a[i], b[n], acc[mh * 4 + i][n], 0, 0, 0, 0x7F7F7F7F, 0, 0x7F7F7F7F);
    }
  };

  const int NT = K / BKB;  // 32
  stage(0, 0);
  stage(1, BKB);

  for (int t = 0; t < NT; ++t) {
    const int cur = t & 1;
    // Drain exactly tile t's 8 loads; tile t+1's 8 stay in flight.
    if (t + 1 < NT) WAITVM(8); else WAITVM(0);
    BARRIER();   // every wave has waited for its tile-t loads -> slot cur ready
    compute(cur);
    BARRIER();   // all waves done reading slot cur -> safe to rewrite
    if (t + 2 < NT) stage(cur, (t + 2) * BKB);
  }

  // Epilogue: C/D 16x16 layout col=lane&15, row=(lane>>4)*4+r (dtype-independent;
  // f8f6f4-scaled C/D layout is shape-determined per m121-m128).
  const int rbase = bm * BM + wr * 128;
  const int cbase = bn * BN + wc * 64;
#pragma unroll
  for (int n = 0; n < 4; ++n) {
    const int col = cbase + n * 16 + fr;
    const float wv = wsc[col];
    const float bb = bf16_rne(bias[col]);  // bias.astype(bf16).astype(f32)
#pragma unroll
    for (int m = 0; m < 8; ++m) {
      const int r0 = rbase + m * 16 + hi * 4;
#pragma unroll
      for (int r = 0; r < 4; ++r) {
        const int row = r0 + r;
        // reference order: (acc * act_scale) * w_scale + bias_bf16, then bf16 RNE
        float v = (acc[m][n][r] * asc[row]) * wv + bb;
        out[(size_t)row * N + col] = bf16_rne(v);
      }
    }
  }
}

extern "C" void kernel_launch(void* const* d_in, const int* in_sizes, int n_in,
                              void* d_out, int out_size, void* d_ws, size_t ws_size,
                              hipStream_t stream) {
  const float* x = (const float*)d_in[0];     // [B,S,K] f32
  const float* w = (const float*)d_in[1];     // [N,K] f32
  const float* bias = (const float*)d_in[2];  // [N] f32
  float* out = (float*)d_out;                 // [M,N] f32 (bf16-rounded values)

  const int N = in_sizes[2];             // 4096 (D_OUT)
  const int K = in_sizes[1] / N;         // 4096 (D_IN)
  const int M = in_sizes[0] / K;         // 8192 tokens

  uint8_t* x8 = (uint8_t*)d_ws;                    // M*K bytes
  uint8_t* w8 = x8 + (size_t)M * K;                // N*K bytes
  float* asc = (float*)(w8 + (size_t)N * K);       // M floats
  float* wsc = asc + M;                            // N floats
  (void)ws_size; (void)n_in; (void)out_size;

  quant_rows_kernel<false><<<M, 256, 0, stream>>>(x, x8, asc, K);
  quant_rows_kernel<true><<<N, 256, 0, stream>>>(w, w8, wsc, K);
  gemm_fp8_kernel<<<(M / BM) * (N / BN), 512, 0, stream>>>(x8, w8, asc, wsc, bias, out, M, N, K);
}